// Round 6
// baseline (181.584 us; speedup 1.0000x reference)
//
#include <hip/hip_runtime.h>

typedef unsigned short u16;
typedef unsigned int   u32;
typedef __bf16 bf16x8 __attribute__((ext_vector_type(8)));
typedef float  f32x4  __attribute__((ext_vector_type(4)));
typedef float  f32x16 __attribute__((ext_vector_type(16)));
typedef u32    u32x4  __attribute__((ext_vector_type(4)));

__device__ __forceinline__ u16 f2bf(float f) {
    return __builtin_bit_cast(u16, (__bf16)f);   // RNE, compiler may pair into v_cvt_pk_bf16_f32
}
__device__ __forceinline__ u32 pk2(float lo, float hi) {
    return (u32)f2bf(lo) | ((u32)f2bf(hi) << 16);
}
// v_permlane32_swap_b32 vdst, vsrc: vdst.lanes[32:63] <-> vsrc.lanes[0:31]
__device__ __forceinline__ void plswap(u32& a, u32& b) {
    asm volatile("v_permlane32_swap_b32 %0, %1" : "+v"(a), "+v"(b));
}

__device__ __forceinline__ void gload16(const void* g, void* lds) {
    __builtin_amdgcn_global_load_lds(
        (const __attribute__((address_space(1))) u32*)g,
        (__attribute__((address_space(3))) u32*)lds, 16, 0, 0);
}

__device__ __forceinline__ f32x4 mfma16(bf16x8 a, bf16x8 b, f32x4 c) {
    return __builtin_amdgcn_mfma_f32_16x16x32_bf16(a, b, c, 0, 0, 0);
}
__device__ __forceinline__ f32x16 mfma32(bf16x8 a, bf16x8 b, f32x16 c) {
    return __builtin_amdgcn_mfma_f32_32x32x16_bf16(a, b, c, 0, 0, 0);
}

// ---------------- fused fp32 -> bf16 convert of all 5 inputs ----------------
__global__ __launch_bounds__(256) void k_cvt5(const float* __restrict__ x,
                                              const float* __restrict__ W1,
                                              const float* __restrict__ W2,
                                              const float* __restrict__ Wg,
                                              const float* __restrict__ Wo,
                                              u16* __restrict__ xb, u16* __restrict__ w1b,
                                              u16* __restrict__ w2b, u16* __restrict__ wgb,
                                              u16* __restrict__ wob) {
    int i = blockIdx.x * 256 + threadIdx.x;
    const float* src; u16* dst; int off;
    if (i < 1048576)      { src = x;  dst = xb;  off = 0; }
    else if (i < 1310720) { src = W1; dst = w1b; off = 1048576; }
    else if (i < 1572864) { src = W2; dst = w2b; off = 1310720; }
    else if (i < 2359296) { src = Wg; dst = wgb; off = 1572864; }
    else                  { src = Wo; dst = wob; off = 2359296; }
    int j = i - off;
    float4 v = ((const float4*)src)[j];
    ushort4 o;
    o.x = f2bf(v.x); o.y = f2bf(v.y); o.z = f2bf(v.z); o.w = f2bf(v.w);
    ((ushort4*)dst)[j] = o;
}

// ---------------- NT GEMM: C[m,n] = sum_k A[m,k]*B[n,k] + bias[n] ----------------
// 128x128 tile, BK=64, 8 waves (2x4), wave tile 64x32 = 4x2 frags of 16x16x32.
// Double-buffered LDS, prefetch-ahead 2-phase: STAGE(t+1); COMPUTE(t); barrier.
// LDS XOR-swizzled (slot ^= row&7) via pre-swizzled global source (m173 pattern).
// Columns col < qcols get scaled by 0.125*log2(e) (pre-scale of attention Q).
template<bool SILU, bool OUT_BF16>
__global__ __launch_bounds__(512) void k_gemm(const u16* __restrict__ A,
                                              const u16* __restrict__ B,
                                              const float* __restrict__ bias,
                                              void* __restrict__ Cout,
                                              int M, int N, int K, int qcols) {
    __shared__ __align__(16) u16 As[2][128 * 64];
    __shared__ __align__(16) u16 Bs[2][128 * 64];
    const int tid = threadIdx.x;
    const int w = tid >> 6, l = tid & 63;
    const int wm = w >> 2, wn = w & 3;           // 2 x 4 wave grid
    const int lr = l & 15, lg = l >> 4;

    // bijective XCD swizzle (grids here are multiples of 8)
    const int nwg = gridDim.x * gridDim.y;
    const int hw = blockIdx.x + gridDim.x * blockIdx.y;
    const int wg = (hw & 7) * (nwg >> 3) + (hw >> 3);
    const int m0 = (wg % gridDim.x) * 128, n0 = (wg / gridDim.x) * 128;

    f32x4 acc[4][2];
#pragma unroll
    for (int i = 0; i < 4; ++i)
#pragma unroll
        for (int j = 0; j < 2; ++j) acc[i][j] = (f32x4){0.f, 0.f, 0.f, 0.f};

    // staging: 32 KB / 512 thr = 4 x 16B chunks each; waves 0-3 -> As, 4-7 -> Bs.
    const int srow = l >> 3;
    const int ss = (l & 7) ^ (srow & 7);
    auto STAGE = [&](int buf, int kt) {
#pragma unroll
        for (int i = 0; i < 4; ++i) {
            const int g = w * 4 + i;
            if (g < 16)
                gload16(&A[(size_t)(m0 + g * 8 + srow) * K + kt * 64 + ss * 8],
                        &As[buf][g * 512]);
            else
                gload16(&B[(size_t)(n0 + (g - 16) * 8 + srow) * K + kt * 64 + ss * 8],
                        &Bs[buf][(g - 16) * 512]);
        }
    };

    const int nkt = K >> 6;
    STAGE(0, 0);
    __syncthreads();
    for (int kt = 0; kt < nkt; ++kt) {
        const int cur = kt & 1;
        if (kt + 1 < nkt) STAGE(cur ^ 1, kt + 1);
#pragma unroll
        for (int s = 0; s < 2; ++s) {
            bf16x8 af[4], bq[2];
#pragma unroll
            for (int f = 0; f < 4; ++f) {
                const int r = wm * 64 + f * 16 + lr;
                af[f] = *(const bf16x8*)&As[cur][r * 64 + (((s * 4 + lg) ^ (r & 7)) * 8)];
            }
#pragma unroll
            for (int n = 0; n < 2; ++n) {
                const int r = wn * 32 + n * 16 + lr;
                bq[n] = *(const bf16x8*)&Bs[cur][r * 64 + (((s * 4 + lg) ^ (r & 7)) * 8)];
            }
#pragma unroll
            for (int mf = 0; mf < 4; ++mf)
#pragma unroll
                for (int nf = 0; nf < 2; ++nf)
                    acc[mf][nf] = mfma16(af[mf], bq[nf], acc[mf][nf]);
        }
        if (kt + 1 < nkt) __syncthreads();
    }

    // epilogue: D col = lane&15, row = (lane>>4)*4 + reg   [verified mapping]
#pragma unroll
    for (int nf = 0; nf < 2; ++nf) {
        const int col = n0 + wn * 32 + nf * 16 + lr;
        const float bv = bias[col];
        const float cs = (col < qcols) ? 0.18033688011112042f : 1.0f;
#pragma unroll
        for (int mf = 0; mf < 4; ++mf) {
#pragma unroll
            for (int r = 0; r < 4; ++r) {
                const int row = m0 + wm * 64 + mf * 16 + lg * 4 + r;
                float v = acc[mf][nf][r] + bv;
                if (SILU) v = v / (1.0f + __expf(-v));
                v *= cs;
                if (OUT_BF16) ((u16*)Cout)[(size_t)row * N + col] = f2bf(v);
                else          ((float*)Cout)[(size_t)row * N + col] = v;
            }
        }
    }
}

// ---------------- V transpose: vt[bh][d][n] = qkv[b, n, 2048 + h*64 + d] ----------------
__global__ __launch_bounds__(256) void k_vt(const u16* __restrict__ qkv,
                                            u16* __restrict__ vt) {
    __shared__ u16 tile[64][66];
    const int bh = blockIdx.y;
    const int b = bh >> 4, h = bh & 15;
    const int n0 = blockIdx.x * 64;
    const int tid = threadIdx.x;
#pragma unroll
    for (int it = 0; it < 16; ++it) {
        int idx = it * 256 + tid;
        int r = idx >> 6, c = idx & 63;
        tile[r][c] = qkv[(size_t)(b * 2048 + n0 + r) * 3072 + 2048 + h * 64 + c];
    }
    __syncthreads();
#pragma unroll
    for (int it = 0; it < 16; ++it) {
        int idx = it * 256 + tid;
        int d = idx >> 6, c = idx & 63;
        vt[(size_t)(bh * 64 + d) * 2048 + n0 + c] = tile[c][d];
    }
}

// ---------------- windowed attention, 32x32 MFMA, in-register P ----------------
// Block = q-tile pair (p, 31-p) of one (b,h); 4 waves: 0-1 tile A, 2-3 tile B,
// each wave owns 32 q-rows. kv tiles of 64, K/V staged once for all waves.
// S^T = mfma(K, Q): D col = q = lane&31 (lane-local softmax), D row = kv =
// (r&3)+8*(r>>2)+4*hi  [verified m74/m101]. P assembled in-register via
// cvt_pk + v_permlane32_swap (m214-v22 recipe); PV = mfma(A=V^T, B=P) keeps
// O col = q lane-local -> ls never leaves the lane (one shfl_xor(32) total).
__global__ __launch_bounds__(256) void k_attn(const u16* __restrict__ qkv,
                                              const u16* __restrict__ vt,
                                              u16* __restrict__ ao) {
    __shared__ __align__(16) u16 Ks[2][64 * 64];
    __shared__ __align__(16) u16 Vs[2][64 * 64];
    // bijective XCD swizzle: cluster 16 p-blocks x 4 heads per XCD
    const int hw = blockIdx.x + 16 * blockIdx.y;        // nwg = 512
    const int logical = (hw & 7) * 64 + (hw >> 3);
    const int p = logical & 15, bh = logical >> 4;
    const int b = bh >> 4, h = bh & 15;
    const int tid = threadIdx.x, w = tid >> 6, l = tid & 63;
    const int l31 = l & 31, hi = l >> 5, l7 = l & 7;
    const int i = (w >> 1) ? (31 - p) : p;      // waves 0-1: tile A, 2-3: tile B
    const int qsub = (w & 1) * 32;
    const int nt = min(i + 2, 32);
    const int ntL = min(33 - p, 32);
    const int qg = i * 64 + qsub + l31;         // this lane's q (global)

    bf16x8 qf[4];                                // Q[q][16s + 8hi + 0..7]
    const size_t qb = (size_t)(b * 2048 + qg) * 3072 + h * 64 + hi * 8;
#pragma unroll
    for (int s = 0; s < 4; ++s) qf[s] = *(const bf16x8*)&qkv[qb + s * 16];

    f32x16 o0 = {}, o1 = {};
    float ls = 0.f;

    // stage kv-tile t (K[kv][d] and V^T[d][kv]), XOR-swizzled via global source
    auto STAGE = [&](int buf, int t) {
        const int j0 = t * 64;
#pragma unroll
        for (int it = 0; it < 2; ++it) {
            const int cbase = it * 256 + w * 64;
            const int c = cbase + l;
            const int row = c >> 3, slot = c & 7;
            const int sw = slot ^ (row & 7);
            gload16(&qkv[(size_t)(b * 2048 + j0 + row) * 3072 + 1024 + h * 64 + sw * 8],
                    &Ks[buf][cbase * 8]);
            gload16(&vt[(size_t)(bh * 64 + row) * 2048 + j0 + sw * 8], &Vs[buf][cbase * 8]);
        }
    };

    STAGE(0, 0);
    __syncthreads();
    for (int t = 0; t < ntL; ++t) {
        const int cur = t & 1;
        if (t + 1 < ntL) STAGE(cur ^ 1, t + 1);
        if (t < nt) {
            const u16* Kc = Ks[cur];
            const u16* Vc = Vs[cur];
            // S^T[kv 0..63][q 0..31] in two 32x32 frags
            f32x16 st0 = {}, st1 = {};
            __builtin_amdgcn_s_setprio(1);
#pragma unroll
            for (int s = 0; s < 4; ++s) {
                const int off = ((2 * s + hi) ^ l7) * 8;
                bf16x8 k0 = *(const bf16x8*)&Kc[l31 * 64 + off];
                bf16x8 k1 = *(const bf16x8*)&Kc[(32 + l31) * 64 + off];
                st0 = mfma32(k0, qf[s], st0);
                st1 = mfma32(k1, qf[s], st1);
            }
            __builtin_amdgcn_s_setprio(0);
            // mask (last tile only) + exp2 + row-sum + pack to bf16 pairs
            const bool dm = (t == nt - 1);
            const int thr = qg + 63 - t * 64;      // mask kv_local > thr
            u32 pka[2][8];
#pragma unroll
            for (int mf = 0; mf < 2; ++mf) {
#pragma unroll
                for (int pp = 0; pp < 8; ++pp) {
                    const int r0 = 2 * pp;
                    float e0 = mf ? st1[r0] : st0[r0];
                    float e1 = mf ? st1[r0 + 1] : st0[r0 + 1];
                    const int kv0 = 32 * mf + (r0 & 3) + 8 * (r0 >> 2) + 4 * hi;
                    if (dm) {
                        e0 = (kv0 > thr) ? -1e30f : e0;
                        e1 = (kv0 + 1 > thr) ? -1e30f : e1;
                    }
                    e0 = exp2f(e0); e1 = exp2f(e1);
                    ls += e0 + e1;
                    pka[mf][pp] = pk2(e0, e1);
                }
            }
            // assemble P B-fragments: exchange halves across lane 32 boundary
#pragma unroll
            for (int mf = 0; mf < 2; ++mf) {
                plswap(pka[mf][0], pka[mf][2]);
                plswap(pka[mf][1], pka[mf][3]);
                plswap(pka[mf][4], pka[mf][6]);
                plswap(pka[mf][5], pka[mf][7]);
            }
            __builtin_amdgcn_s_setprio(1);
#pragma unroll
            for (int s = 0; s < 4; ++s) {
                const int mf = s >> 1, o4 = (s & 1) * 4;
                u32x4 pu = {pka[mf][o4], pka[mf][o4 + 1], pka[mf][o4 + 2], pka[mf][o4 + 3]};
                const bf16x8 pa = __builtin_bit_cast(bf16x8, pu);
                const int off = ((2 * s + hi) ^ l7) * 8;
                bf16x8 v0 = *(const bf16x8*)&Vc[l31 * 64 + off];
                bf16x8 v1 = *(const bf16x8*)&Vc[(32 + l31) * 64 + off];
                o0 = mfma32(v0, pa, o0);
                o1 = mfma32(v1, pa, o1);
            }
            __builtin_amdgcn_s_setprio(0);
        }
        __syncthreads();
    }

    // epilogue: O col = q (lane-local), row d = 32*db + (r&3) + 8*(r>>2) + 4*hi
    ls += __shfl_xor(ls, 32);
    const float li = 1.0f / ls;
    const size_t orow = (size_t)(b * 2048 + qg) * 1024 + h * 64;
#pragma unroll
    for (int db = 0; db < 2; ++db) {
#pragma unroll
        for (int g = 0; g < 4; ++g) {
            float v0 = (db ? o1[4 * g + 0] : o0[4 * g + 0]) * li;
            float v1 = (db ? o1[4 * g + 1] : o0[4 * g + 1]) * li;
            float v2 = (db ? o1[4 * g + 2] : o0[4 * g + 2]) * li;
            float v3 = (db ? o1[4 * g + 3] : o0[4 * g + 3]) * li;
            ushort4 pw;
            pw.x = f2bf(v0); pw.y = f2bf(v1); pw.z = f2bf(v2); pw.w = f2bf(v3);
            const int d0 = db * 32 + g * 8 + hi * 4;
            *(ushort4*)&ao[orow + d0] = pw;
        }
    }
}

extern "C" void kernel_launch(void* const* d_in, const int* in_sizes, int n_in,
                              void* d_out, int out_size, void* d_ws, size_t ws_size,
                              hipStream_t stream) {
    const float* x  = (const float*)d_in[0];
    const float* W1 = (const float*)d_in[1];
    const float* b1 = (const float*)d_in[2];
    const float* W2 = (const float*)d_in[3];
    const float* b2 = (const float*)d_in[4];
    const float* Wg = (const float*)d_in[5];
    const float* bg = (const float*)d_in[6];
    const float* Wo = (const float*)d_in[7];
    const float* bo = (const float*)d_in[8];
    float* out = (float*)d_out;

    char* ws = (char*)d_ws;
    const size_t MB = 1024 * 1024;
    u16* x_bf   = (u16*)(ws + 0);        // 8 MB
    u16* w1_bf  = (u16*)(ws + 8  * MB);  // 2 MB
    u16* w2_bf  = (u16*)(ws + 10 * MB);  // 2 MB
    u16* wg_bf  = (u16*)(ws + 12 * MB);  // 6 MB
    u16* wo_bf  = (u16*)(ws + 18 * MB);  // 2 MB
    u16* h1_bf  = (u16*)(ws + 20 * MB);  // 8 MB
    u16* h_bf   = (u16*)(ws + 28 * MB);  // 8 MB
    u16* qkv_bf = (u16*)(ws + 36 * MB);  // 24 MB
    u16* vt_bf  = (u16*)(ws + 60 * MB);  // 8 MB
    u16* ao_bf  = (u16*)(ws + 68 * MB);  // 8 MB (total 76 MB)

    k_cvt5<<<10240, 256, 0, stream>>>(x, W1, W2, Wg, Wo,
                                      x_bf, w1_bf, w2_bf, wg_bf, wo_bf);

    k_gemm<true,  true ><<<dim3(32, 8),  512, 0, stream>>>(x_bf,  w1_bf, b1, h1_bf,  4096, 1024, 1024, 0);
    k_gemm<false, true ><<<dim3(32, 8),  512, 0, stream>>>(h1_bf, w2_bf, b2, h_bf,   4096, 1024, 1024, 0);
    k_gemm<false, true ><<<dim3(32, 24), 512, 0, stream>>>(h_bf,  wg_bf, bg, qkv_bf, 4096, 3072, 1024, 1024);

    k_vt  <<<dim3(32, 32), 256, 0, stream>>>(qkv_bf, vt_bf);
    k_attn<<<dim3(16, 32), 256, 0, stream>>>(qkv_bf, vt_bf, ao_bf);

    k_gemm<false, false><<<dim3(32, 8), 512, 0, stream>>>(ao_bf, wo_bf, bo, out, 4096, 1024, 1024, 0);
}

// Round 9
// 156.998 us; speedup vs baseline: 1.1566x; 1.1566x over previous
//
#include <hip/hip_runtime.h>

typedef unsigned short u16;
typedef unsigned int   u32;
typedef __bf16 bf16x8 __attribute__((ext_vector_type(8)));
typedef float  f32x4  __attribute__((ext_vector_type(4)));

__device__ __forceinline__ u16 f2bf(float f) {
    return __builtin_bit_cast(u16, (__bf16)f);   // RNE via v_cvt_pk_bf16_f32
}

__device__ __forceinline__ void gload16(const void* g, void* lds) {
    __builtin_amdgcn_global_load_lds(
        (const __attribute__((address_space(1))) u32*)g,
        (__attribute__((address_space(3))) u32*)lds, 16, 0, 0);
}

__device__ __forceinline__ f32x4 mfma16(bf16x8 a, bf16x8 b, f32x4 c) {
    return __builtin_amdgcn_mfma_f32_16x16x32_bf16(a, b, c, 0, 0, 0);
}

// ---------------- fused fp32 -> bf16 convert of all 5 inputs ----------------
__global__ __launch_bounds__(256) void k_cvt5(const float* __restrict__ x,
                                              const float* __restrict__ W1,
                                              const float* __restrict__ W2,
                                              const float* __restrict__ Wg,
                                              const float* __restrict__ Wo,
                                              u16* __restrict__ xb, u16* __restrict__ w1b,
                                              u16* __restrict__ w2b, u16* __restrict__ wgb,
                                              u16* __restrict__ wob) {
    int i = blockIdx.x * 256 + threadIdx.x;
    const float* src; u16* dst; int off;
    if (i < 1048576)      { src = x;  dst = xb;  off = 0; }
    else if (i < 1310720) { src = W1; dst = w1b; off = 1048576; }
    else if (i < 1572864) { src = W2; dst = w2b; off = 1310720; }
    else if (i < 2359296) { src = Wg; dst = wgb; off = 1572864; }
    else                  { src = Wo; dst = wob; off = 2359296; }
    int j = i - off;
    float4 v = ((const float4*)src)[j];
    ushort4 o;
    o.x = f2bf(v.x); o.y = f2bf(v.y); o.z = f2bf(v.z); o.w = f2bf(v.w);
    ((ushort4*)dst)[j] = o;
}

// ---------------- NT GEMM: C[m,n] = sum_k A[m,k]*B[n,k] + bias[n] ----------------
// 128x128 tile, BK=64, 8 waves (2x4), wave tile 64x32 = 4x2 frags of 16x16x32.
// Double-buffered LDS, prefetch-ahead 2-phase. XOR-swizzled via global source.
// Columns col < qcols scaled by 0.125*log2(e) (attention Q pre-scale).
// VTOUT: cols >= 2048 (the V third of qkv) are written TRANSPOSED to
// vtout[bh][d][n] instead of Cout (fuses the old k_vt kernel).
template<bool SILU, bool OUT_BF16, bool VTOUT>
__global__ __launch_bounds__(512) void k_gemm(const u16* __restrict__ A,
                                              const u16* __restrict__ B,
                                              const float* __restrict__ bias,
                                              void* __restrict__ Cout,
                                              int M, int N, int K, int qcols,
                                              u16* __restrict__ vtout) {
    __shared__ __align__(16) u16 As[2][128 * 64];
    __shared__ __align__(16) u16 Bs[2][128 * 64];
    const int tid = threadIdx.x;
    const int w = tid >> 6, l = tid & 63;
    const int wm = w >> 2, wn = w & 3;           // 2 x 4 wave grid
    const int lr = l & 15, lg = l >> 4;

    // bijective XCD swizzle (grids here are multiples of 8)
    const int nwg = gridDim.x * gridDim.y;
    const int hw = blockIdx.x + gridDim.x * blockIdx.y;
    const int wg = (hw & 7) * (nwg >> 3) + (hw >> 3);
    const int m0 = (wg % gridDim.x) * 128, n0 = (wg / gridDim.x) * 128;

    f32x4 acc[4][2];
#pragma unroll
    for (int i = 0; i < 4; ++i)
#pragma unroll
        for (int j = 0; j < 2; ++j) acc[i][j] = (f32x4){0.f, 0.f, 0.f, 0.f};

    const int srow = l >> 3;
    const int ss = (l & 7) ^ (srow & 7);
    auto STAGE = [&](int buf, int kt) {
#pragma unroll
        for (int i = 0; i < 4; ++i) {
            const int g = w * 4 + i;
            if (g < 16)
                gload16(&A[(size_t)(m0 + g * 8 + srow) * K + kt * 64 + ss * 8],
                        &As[buf][g * 512]);
            else
                gload16(&B[(size_t)(n0 + (g - 16) * 8 + srow) * K + kt * 64 + ss * 8],
                        &Bs[buf][(g - 16) * 512]);
        }
    };

    const int nkt = K >> 6;
    STAGE(0, 0);
    __syncthreads();
    for (int kt = 0; kt < nkt; ++kt) {
        const int cur = kt & 1;
        if (kt + 1 < nkt) STAGE(cur ^ 1, kt + 1);
#pragma unroll
        for (int s = 0; s < 2; ++s) {
            bf16x8 af[4], bq[2];
#pragma unroll
            for (int f = 0; f < 4; ++f) {
                const int r = wm * 64 + f * 16 + lr;
                af[f] = *(const bf16x8*)&As[cur][r * 64 + (((s * 4 + lg) ^ (r & 7)) * 8)];
            }
#pragma unroll
            for (int n = 0; n < 2; ++n) {
                const int r = wn * 32 + n * 16 + lr;
                bq[n] = *(const bf16x8*)&Bs[cur][r * 64 + (((s * 4 + lg) ^ (r & 7)) * 8)];
            }
#pragma unroll
            for (int mf = 0; mf < 4; ++mf)
#pragma unroll
                for (int nf = 0; nf < 2; ++nf)
                    acc[mf][nf] = mfma16(af[mf], bq[nf], acc[mf][nf]);
        }
        if (kt + 1 < nkt) __syncthreads();
    }

    // epilogue: D col = lane&15, row = (lane>>4)*4 + reg   [verified mapping]
#pragma unroll
    for (int nf = 0; nf < 2; ++nf) {
        const int col = n0 + wn * 32 + nf * 16 + lr;
        const float bv = bias[col];
        const float cs = (col < qcols) ? 0.18033688011112042f : 1.0f;
#pragma unroll
        for (int mf = 0; mf < 4; ++mf) {
            float vv[4];
#pragma unroll
            for (int r = 0; r < 4; ++r) {
                float v = acc[mf][nf][r] + bv;
                if (SILU) v = v / (1.0f + __expf(-v));
                vv[r] = v * cs;
            }
            const int row0 = m0 + wm * 64 + mf * 16 + lg * 4;
            if (VTOUT && col >= 2048) {
                // transposed V write: vt[(b*16+h)*64 + d][token] (8B aligned)
                const int dfull = col - 2048;
                const int bh = (row0 >> 11) * 16 + (dfull >> 6);
                const int d = dfull & 63;
                const int n = row0 & 2047;
                ushort4 pw;
                pw.x = f2bf(vv[0]); pw.y = f2bf(vv[1]);
                pw.z = f2bf(vv[2]); pw.w = f2bf(vv[3]);
                *(ushort4*)&vtout[(size_t)(bh * 64 + d) * 2048 + n] = pw;
            } else if (OUT_BF16) {
#pragma unroll
                for (int r = 0; r < 4; ++r)
                    ((u16*)Cout)[(size_t)(row0 + r) * N + col] = f2bf(vv[r]);
            } else {
#pragma unroll
                for (int r = 0; r < 4; ++r)
                    ((float*)Cout)[(size_t)(row0 + r) * N + col] = vv[r];
            }
        }
    }
}

// ---------------- windowed attention, split-pair waves (R5, verified) ----------------
// Block = q-tile pair (p, 31-p) of one (b,h); 8 waves: 0-3 own tile A's 64
// q-rows, 4-7 own tile B's. K/V staged once per kv-tile for both sides.
// No running max: Q pre-scaled by 0.125*log2e, p = exp2(S'), unnormalized
// accumulation, one divide at the end.
// S^T = mfma(K, Q): D row = kv, D col = q (lane&15) -> q-sum is lane-local.
__device__ __forceinline__ void attn_leg(const u16* __restrict__ Ksb,
                                         const u16* __restrict__ Vsb,
                                         u16* __restrict__ Plw,
                                         int lr, int lg, bf16x8 q0, bf16x8 q1,
                                         f32x4 (&o)[4], float& ls,
                                         int thr, bool domask) {
    f32x4 st[4];
#pragma unroll
    for (int f = 0; f < 4; ++f) st[f] = (f32x4){0.f, 0.f, 0.f, 0.f};
    __builtin_amdgcn_s_setprio(1);
#pragma unroll
    for (int s = 0; s < 2; ++s) {
        const bf16x8 qf = s ? q1 : q0;
#pragma unroll
        for (int f = 0; f < 4; ++f) {
            const int row = f * 16 + lr;
            const int sw = ((s * 4 + lg) ^ (row & 7)) * 8;
            bf16x8 kf = *(const bf16x8*)&Ksb[row * 64 + sw];
            st[f] = mfma16(kf, qf, st[f]);
        }
    }
    __builtin_amdgcn_s_setprio(0);
    const int kbase = lg * 4;
#pragma unroll
    for (int f = 0; f < 4; ++f) {
        float pv[4];
#pragma unroll
        for (int r = 0; r < 4; ++r) {
            float sv = st[f][r];
            if (domask) sv = (f * 16 + kbase + r > thr) ? -1e30f : sv;
            pv[r] = exp2f(sv);
            ls += pv[r];
        }
        ushort4 pw;
        pw.x = f2bf(pv[0]); pw.y = f2bf(pv[1]); pw.z = f2bf(pv[2]); pw.w = f2bf(pv[3]);
        *(ushort4*)&Plw[lr * 80 + f * 16 + kbase] = pw;   // P[q][kv], stride 80 u16
    }
    __builtin_amdgcn_s_setprio(1);
#pragma unroll
    for (int s = 0; s < 2; ++s) {
        const bf16x8 pf = *(const bf16x8*)&Plw[lr * 80 + s * 32 + lg * 8];
#pragma unroll
        for (int f = 0; f < 4; ++f) {
            const int row = f * 16 + lr;
            const int sw = ((s * 4 + lg) ^ (row & 7)) * 8;
            bf16x8 vf = *(const bf16x8*)&Vsb[row * 64 + sw];
            o[f] = mfma16(pf, vf, o[f]);
        }
    }
    __builtin_amdgcn_s_setprio(0);
}

__global__ __launch_bounds__(512) void k_attn(const u16* __restrict__ qkv,
                                              const u16* __restrict__ vt,
                                              u16* __restrict__ ao) {
    __shared__ __align__(16) u16 Ks[2][64 * 64];
    __shared__ __align__(16) u16 Vs[2][64 * 64];
    __shared__ __align__(16) u16 Pl[8][16 * 80];
    // bijective XCD swizzle: cluster the 16 p-blocks x 4 heads per XCD
    const int hw = blockIdx.x + 16 * blockIdx.y;        // nwg = 512
    const int logical = (hw & 7) * 64 + (hw >> 3);
    const int p = logical & 15, bh = logical >> 4;
    const int b = bh >> 4, h = bh & 15;
    const int tid = threadIdx.x, w = tid >> 6, l = tid & 63;
    const int lr = l & 15, lg = l >> 4;
    const int i = (w >> 2) ? (31 - p) : p;      // waves 0-3: tile A, 4-7: tile B
    const int nt = min(i + 2, 32);              // my wave's kv-tile count
    const int ntL = min(33 - p, 32);            // loop bound = max over waves

    const size_t qb = (size_t)(b * 2048 + i * 64 + (w & 3) * 16 + lr) * 3072 + h * 64;
    const bf16x8 q0 = *(const bf16x8*)&qkv[qb + lg * 8];
    const bf16x8 q1 = *(const bf16x8*)&qkv[qb + 32 + lg * 8];

    f32x4 o[4];
#pragma unroll
    for (int f = 0; f < 4; ++f) o[f] = (f32x4){0.f, 0.f, 0.f, 0.f};
    float ls = 0.f;
    const int ql = i * 64 + (w & 3) * 16 + lr;

    // stage tile t: 512 lanes, one 16B K-chunk + one V-chunk each (swizzled src)
    const int srow = tid >> 3;
    const int ss = (tid & 7) ^ (srow & 7);
    auto STAGE = [&](int buf, int t) {
        const int j0 = t * 64;
        gload16(&qkv[(size_t)(b * 2048 + j0 + srow) * 3072 + 1024 + h * 64 + ss * 8],
                &Ks[buf][tid * 8]);
        gload16(&vt[(size_t)(bh * 64 + srow) * 2048 + j0 + ss * 8], &Vs[buf][tid * 8]);
    };

    STAGE(0, 0);
    __syncthreads();
    for (int t = 0; t < ntL; ++t) {
        const int cur = t & 1;
        if (t + 1 < ntL) STAGE(cur ^ 1, t + 1);
        if (t < nt)
            attn_leg(Ks[cur], Vs[cur], Pl[w], lr, lg, q0, q1, o, ls,
                     ql + 63 - t * 64, t == nt - 1);
        __syncthreads();
    }

    // epilogue: reduce row sums, normalize, write
    ls += __shfl_xor(ls, 16); ls += __shfl_xor(ls, 32);
    float li[4];
#pragma unroll
    for (int r = 0; r < 4; ++r) li[r] = 1.0f / __shfl(ls, lg * 4 + r);
#pragma unroll
    for (int f = 0; f < 4; ++f) {
#pragma unroll
        for (int r = 0; r < 4; ++r) {
            const int row = b * 2048 + i * 64 + (w & 3) * 16 + lg * 4 + r;
            ao[(size_t)row * 1024 + h * 64 + f * 16 + lr] = f2bf(o[f][r] * li[r]);
        }
    }
}

extern "C" void kernel_launch(void* const* d_in, const int* in_sizes, int n_in,
                              void* d_out, int out_size, void* d_ws, size_t ws_size,
                              hipStream_t stream) {
    const float* x  = (const float*)d_in[0];
    const float* W1 = (const float*)d_in[1];
    const float* b1 = (const float*)d_in[2];
    const float* W2 = (const float*)d_in[3];
    const float* b2 = (const float*)d_in[4];
    const float* Wg = (const float*)d_in[5];
    const float* bg = (const float*)d_in[6];
    const float* Wo = (const float*)d_in[7];
    const float* bo = (const float*)d_in[8];
    float* out = (float*)d_out;

    char* ws = (char*)d_ws;
    const size_t MB = 1024 * 1024;
    u16* x_bf   = (u16*)(ws + 0);        // 8 MB
    u16* w1_bf  = (u16*)(ws + 8  * MB);  // 2 MB
    u16* w2_bf  = (u16*)(ws + 10 * MB);  // 2 MB
    u16* wg_bf  = (u16*)(ws + 12 * MB);  // 6 MB
    u16* wo_bf  = (u16*)(ws + 18 * MB);  // 2 MB
    u16* h1_bf  = (u16*)(ws + 20 * MB);  // 8 MB
    u16* h_bf   = (u16*)(ws + 28 * MB);  // 8 MB
    u16* qkv_bf = (u16*)(ws + 36 * MB);  // 24 MB
    u16* vt_bf  = (u16*)(ws + 60 * MB);  // 8 MB
    u16* ao_bf  = (u16*)(ws + 68 * MB);  // 8 MB (total 76 MB)

    k_cvt5<<<10240, 256, 0, stream>>>(x, W1, W2, Wg, Wo,
                                      x_bf, w1_bf, w2_bf, wg_bf, wo_bf);

    k_gemm<true,  true,  false><<<dim3(32, 8),  512, 0, stream>>>(x_bf,  w1_bf, b1, h1_bf,  4096, 1024, 1024, 0, nullptr);
    k_gemm<false, true,  false><<<dim3(32, 8),  512, 0, stream>>>(h1_bf, w2_bf, b2, h_bf,   4096, 1024, 1024, 0, nullptr);
    k_gemm<false, true,  true ><<<dim3(32, 24), 512, 0, stream>>>(h_bf,  wg_bf, bg, qkv_bf, 4096, 3072, 1024, 1024, vt_bf);

    k_attn<<<dim3(16, 32), 512, 0, stream>>>(qkv_bf, vt_bf, ao_bf);

    k_gemm<false, false, false><<<dim3(32, 8), 512, 0, stream>>>(ao_bf, wo_bf, bo, out, 4096, 1024, 1024, 0, nullptr);
}